// Round 14
// baseline (193.881 us; speedup 1.0000x reference)
//
#include <hip/hip_runtime.h>
#include <math.h>

#define HN 8
#define DHD 32
#define NQ 2048
#define NK 2048
#define DIM 256
#define SPITCH 2056  // 2048 + 8 u16 pad

typedef unsigned short u16;
typedef __attribute__((ext_vector_type(8))) short short8;
typedef __attribute__((ext_vector_type(4))) float f32x4;

__device__ __forceinline__ u16 f2b(float f) {
    unsigned int x = __builtin_bit_cast(unsigned int, f);
    x += 0x7fffu + ((x >> 16) & 1u);   // RNE; -inf stays 0xFF80
    return (u16)(x >> 16);
}
__device__ __forceinline__ float h2f(u16 u) {
    return (float)__builtin_bit_cast(_Float16, u);
}

// ---- universal mask element-width detector: W in {1,2,4,8} (r9) ----
__global__ void detect_kernel(const u16* __restrict__ mk, int* flag) {
    __shared__ unsigned int vflags, nzc, halfw, diffpair;
    if (threadIdx.x == 0) { vflags = 0; nzc = 0; halfw = 0; diffpair = 0; }
    __syncthreads();
    unsigned int lv = 0, lnz = 0, lhw = 0, ldp = 0;
    for (int i = threadIdx.x; i < 1024; i += 256) {
        unsigned int v = mk[i];
        if (v) {
            lnz |= 1u << (i & 3);
            unsigned int hi = v >> 8;
            if (hi == 0x01u) lv |= 1u;            // u8 pair signature
            if (v == 0x3F80u) lv |= 2u;           // bf16 1.0
            if (v == 0x3C00u) lv |= 4u;           // f16 1.0
            if (v == 0x0001u) lv |= 8u;           // int 1
            if (v == 0xFFFFu) lv |= 16u;          // -1 family
            if (v == 0x3FF0u) lv |= 32u;          // f64 1.0 high half
        }
    }
    const unsigned int* w32 = (const unsigned int*)mk;
    for (int i = threadIdx.x; i < 512; i += 256) {
        unsigned int w = w32[i];
        unsigned int lo = w & 0xFFFFu, hi2 = w >> 16;
        if ((lo == 0u) != (hi2 == 0u)) lhw = 1u;
        if (!(i & 1) && (i + 1) < 512 && w != w32[i + 1]) ldp = 1u;
    }
    if (lv) atomicOr(&vflags, lv);
    if (lnz) atomicOr(&nzc, lnz);
    if (lhw) atomicOr(&halfw, 1u);
    if (ldp) atomicOr(&diffpair, 1u);
    __syncthreads();
    if (threadIdx.x == 0) {
        unsigned int V = vflags, N = nzc;
        int W;
        if (V & 1u) W = 1;
        else if ((V & 16u) && !(V & (2u | 4u | 8u)))
            W = halfw ? 2 : (diffpair ? 4 : 8);
        else if (V & (2u | 4u))
            W = (N & 0x5u) ? 2 : 4;
        else if (V & 32u) W = 8;
        else if (N == 0xFu) W = 2;
        else if (N == 0x1u) W = 8;
        else W = 4;
        *flag = W;
    }
}

// ---- out = bf16(X @ W^T + b) ; vt=1 stores transposed [DIM][NQ] for V ----
__global__ __launch_bounds__(256) void proj_kernel(
    const float* __restrict__ X, const float* __restrict__ W,
    const float* __restrict__ bias, u16* __restrict__ out, int vt)
{
    int l = threadIdx.x & 63, wv = threadIdx.x >> 6;
    int tile = blockIdx.x * 4 + wv;
    int n0 = (tile >> 4) << 4, o0 = (tile & 15) << 4;
    int lr = l & 15, lg = l >> 4;
    const float* xa = X + (n0 + lr) * DIM + lg * 8;
    const float* wb = W + (o0 + lr) * DIM + lg * 8;
    f32x4 acc = {0.f, 0.f, 0.f, 0.f};
    #pragma unroll
    for (int k = 0; k < DIM / 32; k++) {
        float4 x0 = *(const float4*)(xa + k * 32);
        float4 x1 = *(const float4*)(xa + k * 32 + 4);
        float4 w0 = *(const float4*)(wb + k * 32);
        float4 w1 = *(const float4*)(wb + k * 32 + 4);
        short8 a, b;
        a[0]=(short)f2b(x0.x); a[1]=(short)f2b(x0.y); a[2]=(short)f2b(x0.z); a[3]=(short)f2b(x0.w);
        a[4]=(short)f2b(x1.x); a[5]=(short)f2b(x1.y); a[6]=(short)f2b(x1.z); a[7]=(short)f2b(x1.w);
        b[0]=(short)f2b(w0.x); b[1]=(short)f2b(w0.y); b[2]=(short)f2b(w0.z); b[3]=(short)f2b(w0.w);
        b[4]=(short)f2b(w1.x); b[5]=(short)f2b(w1.y); b[6]=(short)f2b(w1.z); b[7]=(short)f2b(w1.w);
        acc = __builtin_amdgcn_mfma_f32_16x16x32_bf16(a, b, acc, 0, 0, 0);
    }
    float bv = bias[o0 + lr];
    #pragma unroll
    for (int r = 0; r < 4; r++) {
        float v = acc[r] + bv;
        int nr = n0 + lg * 4 + r, oc = o0 + lr;
        if (vt == 0) out[nr * DIM + oc] = f2b(v);
        else         out[oc * NQ + nr] = f2b(v);
    }
}

// ---- fused attention: one block per (head, 16-query tile); f32 outputs ----
__global__ __launch_bounds__(256) void attn_kernel(
    const u16* __restrict__ Qp, const u16* __restrict__ Kp,
    const u16* __restrict__ Vt,
    const float* __restrict__ embed, const float* __restrict__ af,
    const float* __restrict__ kw, const void* __restrict__ masks,
    const int* __restrict__ flag, const float* __restrict__ Wp,
    const float* __restrict__ bp,
    float* __restrict__ outH, float* __restrict__ outA)
{
    __shared__ u16 s[16 * SPITCH];
    __shared__ float redbuf[4 * 16];
    __shared__ float rowstat[16];
    __shared__ float hid[4][16][DHD];

    int h = blockIdx.x >> 7, qt = blockIdx.x & 127;
    int n0 = qt * 16;
    int tid = threadIdx.x, l = tid & 63, wv = tid >> 6;
    int lr = l & 15, lg = l >> 4;
    int W = *flag;                           // mask element width in bytes
    const unsigned char* m8 = (const unsigned char*)masks;
    const u16* m16 = (const u16*)masks;
    const unsigned int* m32 = (const unsigned int*)masks;
    float wp0 = Wp[0], wp1 = Wp[1], wp2 = Wp[2], bpv = bp[0];
    const float rs = 0.17677669529663687f;   // 1/sqrt(32)

    short8 aq = *(const short8*)(Qp + (n0 + lr) * DIM + h * DHD + lg * 8);

    // ---- phase 1: scores = (qk + p) * mu -> LDS (f16), track rounded row max ----
    float vmax[4] = {-INFINITY, -INFINITY, -INFINITY, -INFINITY};
    for (int it = 0; it < 32; it++) {
        int m = it * 64 + wv * 16 + lr;
        short8 bk = *(const short8*)(Kp + m * DIM + h * DHD + lg * 8);
        f32x4 acc = {0.f, 0.f, 0.f, 0.f};
        acc = __builtin_amdgcn_mfma_f32_16x16x32_bf16(aq, bk, acc, 0, 0, 0);
        float w = kw[m] * rs;
        bool msk;                            // reference polarity: True => -inf
        if (W == 1)      msk = m8[m] != 0;
        else if (W == 2) msk = m16[m] != 0;
        else if (W == 4) msk = m32[m] != 0u;
        else             msk = (m32[2 * m] | m32[2 * m + 1]) != 0u;
        #pragma unroll
        for (int r = 0; r < 4; r++) {
            int nl = lg * 4 + r;
            long nm = (long)(n0 + nl) * NK + m;
            const float* ep = embed + nm * 3;
            float p = ep[0] * wp0 + ep[1] * wp1 + ep[2] * wp2 + bpv;
            float mu = af[nm] * w;
            float sv = msk ? -INFINITY : fmaf(acc[r], mu, p * mu);
            _Float16 hh = (_Float16)sv;
            vmax[r] = fmaxf(vmax[r], (float)hh);
            s[nl * SPITCH + m] = __builtin_bit_cast(u16, hh);
        }
    }
    #pragma unroll
    for (int o = 8; o >= 1; o >>= 1) {
        #pragma unroll
        for (int r = 0; r < 4; r++)
            vmax[r] = fmaxf(vmax[r], __shfl_xor(vmax[r], o, 64));
    }
    if (lr == 0) {
        #pragma unroll
        for (int r = 0; r < 4; r++) redbuf[wv * 16 + lg * 4 + r] = vmax[r];
    }
    __syncthreads();
    if (tid < 16)
        rowstat[tid] = fmaxf(fmaxf(redbuf[tid], redbuf[16 + tid]),
                             fmaxf(redbuf[32 + tid], redbuf[48 + tid]));
    __syncthreads();

    // ---- phase 2: row sums ----
    int row = tid >> 4, seg = tid & 15;
    float rm = rowstat[row];
    float ssum = 0.f;
    for (int i = 0; i < 16; i++) {
        union { uint4 v; u16 u[8]; } pk;
        pk.v = *(const uint4*)&s[row * SPITCH + i * 128 + seg * 8];
        #pragma unroll
        for (int j = 0; j < 8; j++) ssum += __expf(h2f(pk.u[j]) - rm);
    }
    #pragma unroll
    for (int o = 8; o >= 1; o >>= 1) ssum += __shfl_xor(ssum, o, 64);
    if (seg == 0) redbuf[row] = ssum;
    __syncthreads();
    float inv = 1.0f / redbuf[row];

    // ---- phase 3: attn f32 -> global ; bf16 -> LDS in place ----
    long abase = ((long)h * NQ + n0 + row) * NK;
    for (int i = 0; i < 16; i++) {
        int mo = i * 128 + seg * 8;
        union { uint4 v; u16 u[8]; } pk, ov;
        float fo[8];
        pk.v = *(const uint4*)&s[row * SPITCH + mo];
        #pragma unroll
        for (int j = 0; j < 8; j++) {
            float e = __expf(h2f(pk.u[j]) - rm) * inv;
            fo[j] = e;
            ov.u[j] = f2b(e);
        }
        *(uint4*)&s[row * SPITCH + mo] = ov.v;       // same thread, same cells: no race
        *(float4*)(outA + abase + mo)     = *(float4*)&fo[0];
        *(float4*)(outA + abase + mo + 4) = *(float4*)&fo[4];
    }
    __syncthreads();

    // ---- phase 4: hidden = P @ V, K-split across 4 waves ----
    f32x4 acc0 = {0.f,0.f,0.f,0.f}, acc1 = {0.f,0.f,0.f,0.f};
    for (int i = 0; i < 16; i++) {
        int mb = wv * 512 + i * 32;
        short8 ap = *(const short8*)&s[lr * SPITCH + mb + lg * 8];
        short8 b0 = *(const short8*)(Vt + (h * DHD + lr) * NK + mb + lg * 8);
        short8 b1 = *(const short8*)(Vt + (h * DHD + 16 + lr) * NK + mb + lg * 8);
        acc0 = __builtin_amdgcn_mfma_f32_16x16x32_bf16(ap, b0, acc0, 0, 0, 0);
        acc1 = __builtin_amdgcn_mfma_f32_16x16x32_bf16(ap, b1, acc1, 0, 0, 0);
    }
    #pragma unroll
    for (int r = 0; r < 4; r++) {
        hid[wv][lg * 4 + r][lr]      = acc0[r];
        hid[wv][lg * 4 + r][16 + lr] = acc1[r];
    }
    __syncthreads();
    {
        int nl = tid >> 4;
        #pragma unroll
        for (int c = tid & 15; c < DHD; c += 16) {
            float v = hid[0][nl][c] + hid[1][nl][c] + hid[2][nl][c] + hid[3][nl][c];
            outH[(n0 + nl) * DIM + h * DHD + c] = v;   // f32, n-major (B,N,D)
        }
    }
}

extern "C" void kernel_launch(void* const* d_in, const int* in_sizes, int n_in,
                              void* d_out, int out_size, void* d_ws, size_t ws_size,
                              hipStream_t stream)
{
    const float* in_q  = (const float*)d_in[0];
    const float* in_k  = (const float*)d_in[1];
    const float* in_v  = (const float*)d_in[2];
    const float* embed = (const float*)d_in[3];
    const float* kw    = (const float*)d_in[4];
    const void*  masks = d_in[5];
    const float* af    = (const float*)d_in[6];
    const float* Wq = (const float*)d_in[7];
    const float* bq = (const float*)d_in[8];
    const float* Wk = (const float*)d_in[9];
    const float* bk = (const float*)d_in[10];
    const float* Wv = (const float*)d_in[11];
    const float* bv = (const float*)d_in[12];
    const float* Wp = (const float*)d_in[13];
    const float* bp = (const float*)d_in[14];

    float* outH = (float*)d_out;                       // f32 outputs!
    float* outA = outH + (size_t)NQ * DIM;

    char* ws = (char*)d_ws;
    int* flag = (int*)ws;
    u16* Qp = (u16*)(ws + 256);
    u16* Kp = Qp + (size_t)NQ * DIM;
    u16* Vt = Kp + (size_t)NQ * DIM;

    detect_kernel<<<1, 256, 0, stream>>>((const u16*)masks, flag);
    proj_kernel<<<512, 256, 0, stream>>>(in_q, Wq, bq, Qp, 0);
    proj_kernel<<<512, 256, 0, stream>>>(in_k, Wk, bk, Kp, 0);
    proj_kernel<<<512, 256, 0, stream>>>(in_v, Wv, bv, Vt, 1);
    attn_kernel<<<1024, 256, 0, stream>>>(Qp, Kp, Vt, embed, af, kw, masks, flag,
                                          Wp, bp, outH, outA);
}

// Round 15
// 135.249 us; speedup vs baseline: 1.4335x; 1.4335x over previous
//
#include <hip/hip_runtime.h>
#include <math.h>

#define HN 8
#define DHD 32
#define NQ 2048
#define NK 2048
#define DIM 256
#define QBLK 8
#define SPITCH 2056  // 2048 + 8 u16 pad

typedef unsigned short u16;
typedef __attribute__((ext_vector_type(8))) short short8;
typedef __attribute__((ext_vector_type(4))) float f32x4;

__device__ __forceinline__ u16 f2b(float f) {
    unsigned int x = __builtin_bit_cast(unsigned int, f);
    x += 0x7fffu + ((x >> 16) & 1u);   // RNE
    return (u16)(x >> 16);
}
__device__ __forceinline__ float h2f(u16 u) {
    return (float)__builtin_bit_cast(_Float16, u);
}

// ---- universal mask element-width detector: W in {1,2,4,8} (r9, proven) ----
__global__ void detect_kernel(const u16* __restrict__ mk, int* flag) {
    __shared__ unsigned int vflags, nzc, halfw, diffpair;
    if (threadIdx.x == 0) { vflags = 0; nzc = 0; halfw = 0; diffpair = 0; }
    __syncthreads();
    unsigned int lv = 0, lnz = 0, lhw = 0, ldp = 0;
    for (int i = threadIdx.x; i < 1024; i += 256) {
        unsigned int v = mk[i];
        if (v) {
            lnz |= 1u << (i & 3);
            unsigned int hi = v >> 8;
            if (hi == 0x01u) lv |= 1u;
            if (v == 0x3F80u) lv |= 2u;
            if (v == 0x3C00u) lv |= 4u;
            if (v == 0x0001u) lv |= 8u;
            if (v == 0xFFFFu) lv |= 16u;
            if (v == 0x3FF0u) lv |= 32u;
        }
    }
    const unsigned int* w32 = (const unsigned int*)mk;
    for (int i = threadIdx.x; i < 512; i += 256) {
        unsigned int w = w32[i];
        unsigned int lo = w & 0xFFFFu, hi2 = w >> 16;
        if ((lo == 0u) != (hi2 == 0u)) lhw = 1u;
        if (!(i & 1) && (i + 1) < 512 && w != w32[i + 1]) ldp = 1u;
    }
    if (lv) atomicOr(&vflags, lv);
    if (lnz) atomicOr(&nzc, lnz);
    if (lhw) atomicOr(&halfw, 1u);
    if (ldp) atomicOr(&diffpair, 1u);
    __syncthreads();
    if (threadIdx.x == 0) {
        unsigned int V = vflags, N = nzc;
        int W;
        if (V & 1u) W = 1;
        else if ((V & 16u) && !(V & (2u | 4u | 8u)))
            W = halfw ? 2 : (diffpair ? 4 : 8);
        else if (V & (2u | 4u))
            W = (N & 0x5u) ? 2 : 4;
        else if (V & 32u) W = 8;
        else if (N == 0xFu) W = 2;
        else if (N == 0x1u) W = 8;
        else W = 4;
        *flag = W;
    }
}

// ---- fold head-invariant terms: mult = af*kw/sqrt(32), padd = p*mult (f16) ----
__global__ __launch_bounds__(256) void prep_kernel(
    const float* __restrict__ embed, const float* __restrict__ af,
    const float* __restrict__ kw, const void* __restrict__ masks,
    const int* __restrict__ flag, const float* __restrict__ Wp,
    const float* __restrict__ bp, u16* __restrict__ multH, u16* __restrict__ paddH)
{
    long t = (long)blockIdx.x * 256 + threadIdx.x;
    long base = t * 8;
    int m0 = (int)(base & (NK - 1));
    int W = *flag;
    const unsigned char* m8 = (const unsigned char*)masks;
    const u16* m16 = (const u16*)masks;
    const unsigned int* m32 = (const unsigned int*)masks;
    float wp0 = Wp[0], wp1 = Wp[1], wp2 = Wp[2], bpv = bp[0];
    const float rs = 0.17677669529663687f;  // 1/sqrt(32)
    union { float4 v[6]; float f[24]; } e;
    const float4* ep = (const float4*)(embed + base * 3);
    #pragma unroll
    for (int i = 0; i < 6; i++) e.v[i] = ep[i];
    union { float4 v[2]; float f[8]; } a, w;
    a.v[0] = *(const float4*)(af + base);
    a.v[1] = *(const float4*)(af + base + 4);
    w.v[0] = *(const float4*)(kw + m0);
    w.v[1] = *(const float4*)(kw + m0 + 4);
    union { uint4 v; u16 u[8]; } om, op;
    #pragma unroll
    for (int i = 0; i < 8; i++) {
        int m = m0 + i;
        bool on;
        if (W == 1)      on = m8[m] != 0;
        else if (W == 2) on = m16[m] != 0;
        else if (W == 4) on = m32[m] != 0u;
        else             on = (m32[2 * m] | m32[2 * m + 1]) != 0u;
        float p = e.f[3*i] * wp0 + e.f[3*i+1] * wp1 + e.f[3*i+2] * wp2 + bpv;
        float mu = a.f[i] * w.f[i] * rs;
        float pa = p * mu;
        if (on) { mu = 0.0f; pa = -INFINITY; }
        _Float16 hm = (_Float16)mu, hp = (_Float16)pa;
        om.u[i] = __builtin_bit_cast(u16, hm);
        op.u[i] = __builtin_bit_cast(u16, hp);
    }
    *(uint4*)(multH + base) = om.v;
    *(uint4*)(paddH + base) = op.v;
}

// ---- out = bf16(X @ W^T + b) ; vt=1 stores transposed [DIM][NQ] for V ----
__global__ __launch_bounds__(256) void proj_kernel(
    const float* __restrict__ X, const float* __restrict__ W,
    const float* __restrict__ bias, u16* __restrict__ out, int vt)
{
    int l = threadIdx.x & 63, wv = threadIdx.x >> 6;
    int tile = blockIdx.x * 4 + wv;
    int n0 = (tile >> 4) << 4, o0 = (tile & 15) << 4;
    int lr = l & 15, lg = l >> 4;
    const float* xa = X + (n0 + lr) * DIM + lg * 8;
    const float* wb = W + (o0 + lr) * DIM + lg * 8;
    f32x4 acc = {0.f, 0.f, 0.f, 0.f};
    #pragma unroll
    for (int k = 0; k < DIM / 32; k++) {
        float4 x0 = *(const float4*)(xa + k * 32);
        float4 x1 = *(const float4*)(xa + k * 32 + 4);
        float4 w0 = *(const float4*)(wb + k * 32);
        float4 w1 = *(const float4*)(wb + k * 32 + 4);
        short8 a, b;
        a[0]=(short)f2b(x0.x); a[1]=(short)f2b(x0.y); a[2]=(short)f2b(x0.z); a[3]=(short)f2b(x0.w);
        a[4]=(short)f2b(x1.x); a[5]=(short)f2b(x1.y); a[6]=(short)f2b(x1.z); a[7]=(short)f2b(x1.w);
        b[0]=(short)f2b(w0.x); b[1]=(short)f2b(w0.y); b[2]=(short)f2b(w0.z); b[3]=(short)f2b(w0.w);
        b[4]=(short)f2b(w1.x); b[5]=(short)f2b(w1.y); b[6]=(short)f2b(w1.z); b[7]=(short)f2b(w1.w);
        acc = __builtin_amdgcn_mfma_f32_16x16x32_bf16(a, b, acc, 0, 0, 0);
    }
    float bv = bias[o0 + lr];
    #pragma unroll
    for (int r = 0; r < 4; r++) {
        float v = acc[r] + bv;
        int nr = n0 + lg * 4 + r, oc = o0 + lr;
        if (vt == 0) out[nr * DIM + oc] = f2b(v);
        else         out[oc * NQ + nr] = f2b(v);
    }
}

// ---- fused attention v2: one block per (head, 8-query tile); 37 KB LDS ----
__global__ __launch_bounds__(256) void attn2_kernel(
    const u16* __restrict__ Qp, const u16* __restrict__ Kp,
    const u16* __restrict__ Vt,
    const u16* __restrict__ multH, const u16* __restrict__ paddH,
    float* __restrict__ outH, float* __restrict__ outA)
{
    __shared__ u16 s[QBLK * SPITCH];        // 32896 B
    __shared__ float rowstat[QBLK];
    __shared__ float rowsum[QBLK];
    __shared__ float hid[4][QBLK][DHD];     // 4096 B

    int h = blockIdx.x >> 8, qt = blockIdx.x & 255;
    int n0 = qt * QBLK;
    int tid = threadIdx.x, l = tid & 63, wv = tid >> 6;
    int lr = l & 15, lg = l >> 4;

    // A rows 8-15 duplicate 0-7 (QBLK=8); D rows >=8 discarded
    short8 aq = *(const short8*)(Qp + (n0 + (lr & 7)) * DIM + h * DHD + lg * 8);

    // ---- phase 1: raw qk -> LDS f16 ----
    for (int it = 0; it < 32; it++) {
        int m = it * 64 + wv * 16 + lr;
        short8 bk = *(const short8*)(Kp + m * DIM + h * DHD + lg * 8);
        f32x4 acc = {0.f, 0.f, 0.f, 0.f};
        acc = __builtin_amdgcn_mfma_f32_16x16x32_bf16(aq, bk, acc, 0, 0, 0);
        #pragma unroll
        for (int r = 0; r < 4; r++) {
            int nl = lg * 4 + r;
            if (nl < QBLK) {
                _Float16 hh = (_Float16)acc[r];
                s[nl * SPITCH + m] = __builtin_bit_cast(u16, hh);
            }
        }
    }
    __syncthreads();

    // ---- phase 2: apply mult/padd (vectorized f16x8), rounded row max ----
    int row = tid >> 5, seg = tid & 31;
    long nmbase = (long)(n0 + row) * NK;
    u16* srow = s + row * SPITCH;
    float lmax = -INFINITY;
    #pragma unroll
    for (int i = 0; i < 8; i++) {
        int c = i * 256 + seg * 8;
        union { uint4 v; u16 u[8]; } qv, mv, pv, ov;
        qv.v = *(const uint4*)&srow[c];
        mv.v = *(const uint4*)(multH + nmbase + c);
        pv.v = *(const uint4*)(paddH + nmbase + c);
        #pragma unroll
        for (int j = 0; j < 8; j++) {
            float sv = fmaf(h2f(qv.u[j]), h2f(mv.u[j]), h2f(pv.u[j]));
            _Float16 hh = (_Float16)sv;
            lmax = fmaxf(lmax, (float)hh);
            ov.u[j] = __builtin_bit_cast(u16, hh);
        }
        *(uint4*)&srow[c] = ov.v;
    }
    #pragma unroll
    for (int o = 16; o >= 1; o >>= 1) lmax = fmaxf(lmax, __shfl_xor(lmax, o, 32));
    if (seg == 0) rowstat[row] = lmax;
    __syncthreads();
    float rm = rowstat[row];

    // ---- phase 3: exp-sum ----
    float ssum = 0.f;
    #pragma unroll
    for (int i = 0; i < 8; i++) {
        int c = i * 256 + seg * 8;
        union { uint4 v; u16 u[8]; } qv;
        qv.v = *(const uint4*)&srow[c];
        #pragma unroll
        for (int j = 0; j < 8; j++) ssum += __expf(h2f(qv.u[j]) - rm);
    }
    #pragma unroll
    for (int o = 16; o >= 1; o >>= 1) ssum += __shfl_xor(ssum, o, 32);
    if (seg == 0) rowsum[row] = ssum;
    __syncthreads();
    float inv = 1.0f / rowsum[row];

    // ---- phase 4: normalize: f32 -> outA, bf16 -> LDS in place ----
    long abase = ((long)h * NQ + n0 + row) * NK;
    #pragma unroll
    for (int i = 0; i < 8; i++) {
        int c = i * 256 + seg * 8;
        union { uint4 v; u16 u[8]; } qv, ov;
        float fo[8];
        qv.v = *(const uint4*)&srow[c];
        #pragma unroll
        for (int j = 0; j < 8; j++) {
            float e2 = __expf(h2f(qv.u[j]) - rm) * inv;
            fo[j] = e2;
            ov.u[j] = f2b(e2);
        }
        *(uint4*)&srow[c] = ov.v;            // same thread, same cells: no race
        *(float4*)(outA + abase + c)     = *(float4*)&fo[0];
        *(float4*)(outA + abase + c + 4) = *(float4*)&fo[4];
    }
    __syncthreads();

    // ---- phase 5: hidden = P @ V, K-split across 4 waves ----
    f32x4 acc0 = {0.f,0.f,0.f,0.f}, acc1 = {0.f,0.f,0.f,0.f};
    for (int i = 0; i < 16; i++) {
        int mb = wv * 512 + i * 32;
        short8 ap = *(const short8*)&s[(lr & 7) * SPITCH + mb + lg * 8];
        short8 b0 = *(const short8*)(Vt + (h * DHD + lr) * NK + mb + lg * 8);
        short8 b1 = *(const short8*)(Vt + (h * DHD + 16 + lr) * NK + mb + lg * 8);
        acc0 = __builtin_amdgcn_mfma_f32_16x16x32_bf16(ap, b0, acc0, 0, 0, 0);
        acc1 = __builtin_amdgcn_mfma_f32_16x16x32_bf16(ap, b1, acc1, 0, 0, 0);
    }
    #pragma unroll
    for (int r = 0; r < 4; r++) {
        int nl = lg * 4 + r;
        if (nl < QBLK) {
            hid[wv][nl][lr]      = acc0[r];
            hid[wv][nl][16 + lr] = acc1[r];
        }
    }
    __syncthreads();
    {
        int nl = tid >> 5, c = tid & 31;
        float v = hid[0][nl][c] + hid[1][nl][c] + hid[2][nl][c] + hid[3][nl][c];
        outH[(n0 + nl) * DIM + h * DHD + c] = v;   // f32, n-major (B,N,D)
    }
}

extern "C" void kernel_launch(void* const* d_in, const int* in_sizes, int n_in,
                              void* d_out, int out_size, void* d_ws, size_t ws_size,
                              hipStream_t stream)
{
    const float* in_q  = (const float*)d_in[0];
    const float* in_k  = (const float*)d_in[1];
    const float* in_v  = (const float*)d_in[2];
    const float* embed = (const float*)d_in[3];
    const float* kw    = (const float*)d_in[4];
    const void*  masks = d_in[5];
    const float* af    = (const float*)d_in[6];
    const float* Wq = (const float*)d_in[7];
    const float* bq = (const float*)d_in[8];
    const float* Wk = (const float*)d_in[9];
    const float* bk = (const float*)d_in[10];
    const float* Wv = (const float*)d_in[11];
    const float* bv = (const float*)d_in[12];
    const float* Wp = (const float*)d_in[13];
    const float* bp = (const float*)d_in[14];

    float* outH = (float*)d_out;                       // f32 outputs
    float* outA = outH + (size_t)NQ * DIM;

    char* ws = (char*)d_ws;
    int* flag  = (int*)ws;
    u16* Qp    = (u16*)(ws + 256);
    u16* Kp    = Qp + (size_t)NQ * DIM;
    u16* Vt    = Kp + (size_t)NQ * DIM;
    u16* multH = Vt + (size_t)DIM * NK;
    u16* paddH = multH + (size_t)NQ * NK;
    // ws use: 256 B + 3 MiB + 16 MiB = ~19.1 MB

    detect_kernel<<<1, 256, 0, stream>>>((const u16*)masks, flag);
    prep_kernel<<<(NQ * NK / 8) / 256, 256, 0, stream>>>(embed, af, kw, masks, flag,
                                                         Wp, bp, multH, paddH);
    proj_kernel<<<512, 256, 0, stream>>>(in_q, Wq, bq, Qp, 0);
    proj_kernel<<<512, 256, 0, stream>>>(in_k, Wk, bk, Kp, 0);
    proj_kernel<<<512, 256, 0, stream>>>(in_v, Wv, bv, Vt, 1);
    attn2_kernel<<<2048, 256, 0, stream>>>(Qp, Kp, Vt, multH, paddH, outH, outA);
}